// Round 4
// baseline (571.704 us; speedup 1.0000x reference)
//
#include <hip/hip_runtime.h>
#include <hip/hip_bf16.h>
#include <stdint.h>
#include <math.h>

// ---------------- types / helpers ----------------
typedef __attribute__((ext_vector_type(8))) short bf16x8;   // 8 bf16 in 4 VGPRs
typedef __attribute__((ext_vector_type(4))) float f32x4;

#define AS1 __attribute__((address_space(1)))
#define AS3 __attribute__((address_space(3)))

__device__ __forceinline__ ushort f2bf(float f) {
  union { float f; uint32_t u; } in; in.f = f;
  uint32_t u = in.u;
  uint32_t r = u + 0x7fffu + ((u >> 16) & 1u);   // RNE; inputs finite
  return (ushort)(r >> 16);
}
__device__ __forceinline__ float bf2f(ushort h) {
  union { uint32_t u; float f; } out; out.u = ((uint32_t)h) << 16;
  return out.f;
}

// ---------------- cast f32 -> bf16 (vectorized) ----------------
__global__ __launch_bounds__(256)
void cast_f32_bf16(const float4* __restrict__ in, ushort4* __restrict__ out, int n4) {
  int i = blockIdx.x * blockDim.x + threadIdx.x;
  int stride = gridDim.x * blockDim.x;
  for (; i < n4; i += stride) {
    float4 v = in[i];
    ushort4 o;
    o.x = f2bf(v.x); o.y = f2bf(v.y); o.z = f2bf(v.z); o.w = f2bf(v.w);
    out[i] = o;
  }
}

// ---------------- V (B,LK,D) f32 -> Vt (B,D,LK) bf16 ----------------
__global__ __launch_bounds__(256)
void transpose_cast_v(const float* __restrict__ V, ushort* __restrict__ Vt) {
  __shared__ ushort tile[32][33];                // +1 pad: no bank conflicts
  const int b  = blockIdx.z;
  const int k0 = blockIdx.x * 32;
  const int d0 = blockIdx.y * 32;
  const int tx = threadIdx.x;                    // 0..31
  const int ty = threadIdx.y;                    // 0..7
  const float* Vb = V + ((size_t)b * 1024 + k0) * 1024 + d0;
  #pragma unroll
  for (int r = 0; r < 4; ++r) {
    int k = ty * 4 + r;
    tile[k][tx] = f2bf(Vb[(size_t)k * 1024 + tx]);
  }
  __syncthreads();
  ushort* Vtb = Vt + ((size_t)b * 1024 + d0) * 1024 + k0;
  #pragma unroll
  for (int r = 0; r < 4; ++r) {
    int d = ty * 4 + r;
    Vtb[(size_t)d * 1024 + tx] = tile[tx][d];
  }
}

// ---------------- masked softmax over each (b,q) row of S (bf16 in/out) ----
__global__ __launch_bounds__(256)
void softmax_mask(const ushort* __restrict__ S, ushort* __restrict__ P,
                  const float* __restrict__ mask) {
  const int rowId = blockIdx.x;                  // 0..B*LQ-1
  const int b = rowId >> 10;                     // LQ = 1024
  const ushort4* srow = (const ushort4*)(S + (size_t)rowId * 1024);
  const float4* mrow = (const float4*)(mask + (size_t)b * 1024);
  const int t = threadIdx.x;
  const int wid = t >> 6, lane = t & 63;

  ushort4 sv = srow[t];
  float4 mv = mrow[t];
  float s[4] = {bf2f(sv.x), bf2f(sv.y), bf2f(sv.z), bf2f(sv.w)};
  float m[4] = {mv.x, mv.y, mv.z, mv.w};

  float mx = -INFINITY;
  #pragma unroll
  for (int i = 0; i < 4; ++i) if (m[i] != 0.f) mx = fmaxf(mx, s[i]);
  #pragma unroll
  for (int off = 32; off > 0; off >>= 1)
    mx = fmaxf(mx, __shfl_xor(mx, off));

  __shared__ float wred[4][2];
  if (lane == 0) wred[wid][0] = mx;
  __syncthreads();
  float M = fmaxf(fmaxf(wred[0][0], wred[1][0]), fmaxf(wred[2][0], wred[3][0]));

  float e[4]; float sum = 0.f;
  #pragma unroll
  for (int i = 0; i < 4; ++i) {
    e[i] = (m[i] != 0.f) ? __expf(s[i] - M) : 0.f;
    sum += e[i];
  }
  #pragma unroll
  for (int off = 32; off > 0; off >>= 1)
    sum += __shfl_xor(sum, off);
  if (lane == 0) wred[wid][1] = sum;
  __syncthreads();
  float Z = wred[0][1] + wred[1][1] + wred[2][1] + wred[3][1];
  float inv = (Z > 0.f) ? 1.f / Z : 0.f;

  ushort4 o;
  o.x = f2bf(e[0] * inv); o.y = f2bf(e[1] * inv);
  o.z = f2bf(e[2] * inv); o.w = f2bf(e[3] * inv);
  ((ushort4*)(P + (size_t)rowId * 1024))[t] = o;
}

// ---------------- GEMM 256x256, BK=32, 8 waves, 3-deep ring pipeline ------
// C = A(Mx1024,row) * Bt(1024x1024,row)^T.
// Ring of 3 (A,B) slot pairs, prefetch distance 3 K-tiles (~2.5 tile-times
// lead > HBM latency).  Per K-tile, 2 barriers:
//   12 ds_reads -> MFMA1(16, a0-3) -> lgkmcnt(0) -> barrier(mid)
//   -> STAGE A,B(kt+3) in-place into just-read slot -> MFMA2(16, a4-7)
//   -> vmcnt(8) -> barrier(end)
// In-place stage is race-free: every wave drains lgkmcnt(0) before mid-barrier.
// vmcnt(8): <=12 outstanding (3 tiles x 4 loads); oldest 4 = A/B(kt+1).
// LDS swizzle involution on 16B slots: byte ^= ((byte>>3)&0x30)  (rule #21).
// EPI: 0 -> outBf = bf16(acc*scale)                              (S)
//      1 -> outBf = bf16(bf2f(auxBf) + acc)                      (X = Q + PV)
//      2 -> outBf = bf16(relu(acc + bias[col]))                  (FFN1 -> h)
//      3 -> outF  = acc + bias[col] + bf2f(auxBf)                (FFN2 + residual)
template<int EPI>
__global__ __launch_bounds__(512, 2)
void gemm256(const ushort* __restrict__ A, const ushort* __restrict__ Bt,
             size_t aBatch, size_t bBatch, size_t oBatch,
             float scale,
             ushort* outBf, float* outF, const ushort* auxBf,
             const float* __restrict__ bias)
{
  constexpr int K = 1024, N = 1024, NT = 32;    // K-tiles of 32
  __shared__ ushort lds[3][2][8192];            // [ring][A=0,B=1][256*32] = 96 KiB
  const int t = threadIdx.x;
  const int w = t >> 6, lane = t & 63;
  const int wr = w >> 2, wc = w & 3;            // 2 x 4 waves -> 128x64 per wave
  const int lr16 = lane & 15, kg = lane >> 4;

  // T1: XCD-aware bijective remap (nwg is a multiple of 8 for all our grids)
  const unsigned nx = gridDim.x, ny = gridDim.y;
  unsigned flat = blockIdx.x + nx * (blockIdx.y + ny * blockIdx.z);
  const unsigned nwg = nx * ny * gridDim.z;
  const unsigned cpx = nwg >> 3;
  unsigned nf = (flat & 7u) * cpx + (flat >> 3);
  const unsigned bxi = nf % nx;
  const unsigned rest = nf / nx;
  const unsigned byi = rest % ny;
  const unsigned bz = rest / ny;
  const int m0 = byi * 256, n0 = bxi * 256;

  const char* Ab = (const char*)(A + (size_t)bz * aBatch + (size_t)m0 * K);
  const char* Bb = (const char*)(Bt + (size_t)bz * bBatch + (size_t)n0 * K);

  // staging decode: thread stages two 16B chunks per (matrix, K-tile)
  // chunk lds-byte y -> unswizzled tile-byte tb -> global (row, colb)
  const int y0f = (w * 2 + 0) * 1024 + lane * 16;
  const int y1f = (w * 2 + 1) * 1024 + lane * 16;
  const int tb0 = y0f ^ ((y0f >> 3) & 0x30);
  const int tb1 = y1f ^ ((y1f >> 3) & 0x30);
  const int g0 = (tb0 >> 6) * 2048 + (tb0 & 63);   // row*ldBytes + col_byte
  const int g1 = (tb1 >> 6) * 2048 + (tb1 & 63);
  const int l0 = (w * 2 + 0) * 1024;               // wave-uniform LDS byte base
  const int l1 = (w * 2 + 1) * 1024;

  auto STAGE = [&](int ring, int matc, const char* Gb, int kt) {
    char* base = (char*)&lds[ring][matc][0];
    __builtin_amdgcn_global_load_lds(
        (const AS1 void*)(Gb + g0 + kt * 64), (AS3 void*)(base + l0), 16, 0, 0);
    __builtin_amdgcn_global_load_lds(
        (const AS1 void*)(Gb + g1 + kt * 64), (AS3 void*)(base + l1), 16, 0, 0);
  };

  // fragment read offsets (swizzled): slot = kg ^ ((lr16>>1)&3)
  const int slotB = (kg ^ ((lr16 >> 1) & 3)) << 4;
  const int aOff = (wr * 128 + lr16) * 64 + slotB;
  const int bOff = (wc * 64 + lr16) * 64 + slotB;

  auto LDA = [&](int ring, int mi) -> bf16x8 {
    return *(const bf16x8*)((const char*)&lds[ring][0][0] + aOff + mi * 1024);
  };
  auto LDB = [&](int ring, int ni) -> bf16x8 {
    return *(const bf16x8*)((const char*)&lds[ring][1][0] + bOff + ni * 1024);
  };

  f32x4 acc[8][4];
  #pragma unroll
  for (int i = 0; i < 8; ++i)
    #pragma unroll
    for (int j = 0; j < 4; ++j)
      acc[i][j] = (f32x4){0.f, 0.f, 0.f, 0.f};

  // prologue: fill all 3 ring slots (A/B tiles 0,1,2); wait slot 0 (8 in flight)
  STAGE(0, 0, Ab, 0); STAGE(0, 1, Bb, 0);
  STAGE(1, 0, Ab, 1); STAGE(1, 1, Bb, 1);
  STAGE(2, 0, Ab, 2); STAGE(2, 1, Bb, 2);
  asm volatile("s_waitcnt vmcnt(8)" ::: "memory");
  __builtin_amdgcn_s_barrier();

  int s = 0;
  #pragma unroll 1
  for (int kt = 0; kt < NT; ++kt) {
    // ---- phase 0: all 12 fragment reads from ring slot s ----
    bf16x8 b0 = LDB(s, 0), b1 = LDB(s, 1), b2 = LDB(s, 2), b3 = LDB(s, 3);
    bf16x8 a0 = LDA(s, 0), a1 = LDA(s, 1), a2 = LDA(s, 2), a3 = LDA(s, 3);
    bf16x8 a4 = LDA(s, 4), a5 = LDA(s, 5), a6 = LDA(s, 6), a7 = LDA(s, 7);
    __builtin_amdgcn_s_setprio(1);
    acc[0][0] = __builtin_amdgcn_mfma_f32_16x16x32_bf16(a0, b0, acc[0][0], 0, 0, 0);
    acc[0][1] = __builtin_amdgcn_mfma_f32_16x16x32_bf16(a0, b1, acc[0][1], 0, 0, 0);
    acc[0][2] = __builtin_amdgcn_mfma_f32_16x16x32_bf16(a0, b2, acc[0][2], 0, 0, 0);
    acc[0][3] = __builtin_amdgcn_mfma_f32_16x16x32_bf16(a0, b3, acc[0][3], 0, 0, 0);
    acc[1][0] = __builtin_amdgcn_mfma_f32_16x16x32_bf16(a1, b0, acc[1][0], 0, 0, 0);
    acc[1][1] = __builtin_amdgcn_mfma_f32_16x16x32_bf16(a1, b1, acc[1][1], 0, 0, 0);
    acc[1][2] = __builtin_amdgcn_mfma_f32_16x16x32_bf16(a1, b2, acc[1][2], 0, 0, 0);
    acc[1][3] = __builtin_amdgcn_mfma_f32_16x16x32_bf16(a1, b3, acc[1][3], 0, 0, 0);
    acc[2][0] = __builtin_amdgcn_mfma_f32_16x16x32_bf16(a2, b0, acc[2][0], 0, 0, 0);
    acc[2][1] = __builtin_amdgcn_mfma_f32_16x16x32_bf16(a2, b1, acc[2][1], 0, 0, 0);
    acc[2][2] = __builtin_amdgcn_mfma_f32_16x16x32_bf16(a2, b2, acc[2][2], 0, 0, 0);
    acc[2][3] = __builtin_amdgcn_mfma_f32_16x16x32_bf16(a2, b3, acc[2][3], 0, 0, 0);
    acc[3][0] = __builtin_amdgcn_mfma_f32_16x16x32_bf16(a3, b0, acc[3][0], 0, 0, 0);
    acc[3][1] = __builtin_amdgcn_mfma_f32_16x16x32_bf16(a3, b1, acc[3][1], 0, 0, 0);
    acc[3][2] = __builtin_amdgcn_mfma_f32_16x16x32_bf16(a3, b2, acc[3][2], 0, 0, 0);
    acc[3][3] = __builtin_amdgcn_mfma_f32_16x16x32_bf16(a3, b3, acc[3][3], 0, 0, 0);
    __builtin_amdgcn_s_setprio(0);
    // all waves drain LDS reads before anyone overwrites slot s
    asm volatile("s_waitcnt lgkmcnt(0)" ::: "memory");
    __builtin_amdgcn_s_barrier();
    __builtin_amdgcn_sched_barrier(0);
    // ---- phase 1: in-place prefetch of K-tile kt+3 into slot s ----
    int kn = kt + 3 < NT ? kt + 3 : NT - 1;      // clamped dummies keep vmcnt uniform
    STAGE(s, 0, Ab, kn);
    STAGE(s, 1, Bb, kn);
    __builtin_amdgcn_s_setprio(1);
    acc[4][0] = __builtin_amdgcn_mfma_f32_16x16x32_bf16(a4, b0, acc[4][0], 0, 0, 0);
    acc[4][1] = __builtin_amdgcn_mfma_f32_16x16x32_bf16(a4, b1, acc[4][1], 0, 0, 0);
    acc[4][2] = __builtin_amdgcn_mfma_f32_16x16x32_bf16(a4, b2, acc[4][2], 0, 0, 0);
    acc[4][3] = __builtin_amdgcn_mfma_f32_16x16x32_bf16(a4, b3, acc[4][3], 0, 0, 0);
    acc[5][0] = __builtin_amdgcn_mfma_f32_16x16x32_bf16(a5, b0, acc[5][0], 0, 0, 0);
    acc[5][1] = __builtin_amdgcn_mfma_f32_16x16x32_bf16(a5, b1, acc[5][1], 0, 0, 0);
    acc[5][2] = __builtin_amdgcn_mfma_f32_16x16x32_bf16(a5, b2, acc[5][2], 0, 0, 0);
    acc[5][3] = __builtin_amdgcn_mfma_f32_16x16x32_bf16(a5, b3, acc[5][3], 0, 0, 0);
    acc[6][0] = __builtin_amdgcn_mfma_f32_16x16x32_bf16(a6, b0, acc[6][0], 0, 0, 0);
    acc[6][1] = __builtin_amdgcn_mfma_f32_16x16x32_bf16(a6, b1, acc[6][1], 0, 0, 0);
    acc[6][2] = __builtin_amdgcn_mfma_f32_16x16x32_bf16(a6, b2, acc[6][2], 0, 0, 0);
    acc[6][3] = __builtin_amdgcn_mfma_f32_16x16x32_bf16(a6, b3, acc[6][3], 0, 0, 0);
    acc[7][0] = __builtin_amdgcn_mfma_f32_16x16x32_bf16(a7, b0, acc[7][0], 0, 0, 0);
    acc[7][1] = __builtin_amdgcn_mfma_f32_16x16x32_bf16(a7, b1, acc[7][1], 0, 0, 0);
    acc[7][2] = __builtin_amdgcn_mfma_f32_16x16x32_bf16(a7, b2, acc[7][2], 0, 0, 0);
    acc[7][3] = __builtin_amdgcn_mfma_f32_16x16x32_bf16(a7, b3, acc[7][3], 0, 0, 0);
    __builtin_amdgcn_s_setprio(0);
    // oldest 4 loads (A/B(kt+1), issued 2.5 tiles ago) must have landed
    asm volatile("s_waitcnt vmcnt(8)" ::: "memory");
    __builtin_amdgcn_s_barrier();
    s = (s + 1 == 3) ? 0 : s + 1;
  }

  // epilogue: C/D layout col=lane&15, row=(lane>>4)*4+j  [m89-verified]
  const int lr4 = kg * 4;
  #pragma unroll
  for (int mi = 0; mi < 8; ++mi) {
    #pragma unroll
    for (int ni = 0; ni < 4; ++ni) {
      int row = m0 + wr * 128 + mi * 16 + lr4;
      int col = n0 + wc * 64 + ni * 16 + lr16;
      size_t o = (size_t)bz * oBatch + (size_t)row * N + col;
      f32x4 v = acc[mi][ni];
      #pragma unroll
      for (int j = 0; j < 4; ++j) {
        size_t oo = o + (size_t)j * N;
        float x = v[j];
        if (EPI == 0) {
          outBf[oo] = f2bf(x * scale);
        } else if (EPI == 1) {
          outBf[oo] = f2bf(bf2f(auxBf[oo]) + x);
        } else if (EPI == 2) {
          float h = x + bias[col];
          h = h > 0.f ? h : 0.f;
          outBf[oo] = f2bf(h);
        } else {
          outF[oo] = x + bias[col] + bf2f(auxBf[oo]);
        }
      }
    }
  }
}

// ---------------- launch ----------------
extern "C" void kernel_launch(void* const* d_in, const int* in_sizes, int n_in,
                              void* d_out, int out_size, void* d_ws, size_t ws_size,
                              hipStream_t stream) {
  (void)in_sizes; (void)n_in; (void)out_size; (void)ws_size;
  const float* Q  = (const float*)d_in[0];
  const float* Km = (const float*)d_in[1];
  const float* V  = (const float*)d_in[2];
  const float* Vm = (const float*)d_in[3];
  const float* W1 = (const float*)d_in[4];
  const float* b1 = (const float*)d_in[5];
  const float* W2 = (const float*)d_in[6];
  const float* b2 = (const float*)d_in[7];
  float* out = (float*)d_out;

  const int LQ = 1024, LK = 1024, D = 1024;
  const size_t NQ = (size_t)32 * LQ * D;            // 33.5M elems

  // workspace layout (MiB offsets): Qb 0..64, Kb/hb 64..128, Vt 128..192,
  // Sb 192..256, P 256..320, Xb 320..384, W1b 384..386, W2b 386..388
  char* ws = (char*)d_ws;
  ushort* Qb  = (ushort*)(ws);
  ushort* Kb  = (ushort*)(ws + ((size_t)64 << 20));
  ushort* hb  = Kb;                                  // reuse (Kb dead after S-GEMM)
  ushort* Vt  = (ushort*)(ws + ((size_t)128 << 20));
  ushort* Sb  = (ushort*)(ws + ((size_t)192 << 20));
  ushort* P   = (ushort*)(ws + ((size_t)256 << 20));
  ushort* Xb  = (ushort*)(ws + ((size_t)320 << 20));
  ushort* W1b = (ushort*)(ws + ((size_t)384 << 20));
  ushort* W2b = (ushort*)(ws + ((size_t)386 << 20));

  const float inv_scale = 1.0f / (sqrtf(1024.0f) + 1e-8f);

  cast_f32_bf16<<<2048, 256, 0, stream>>>((const float4*)Q,  (ushort4*)Qb, (int)(NQ / 4));
  cast_f32_bf16<<<2048, 256, 0, stream>>>((const float4*)Km, (ushort4*)Kb, (int)(NQ / 4));
  cast_f32_bf16<<<256, 256, 0, stream>>>((const float4*)W1, (ushort4*)W1b, (1024 * 1024) / 4);
  cast_f32_bf16<<<256, 256, 0, stream>>>((const float4*)W2, (ushort4*)W2b, (1024 * 1024) / 4);
  transpose_cast_v<<<dim3(32, 32, 32), dim3(32, 8), 0, stream>>>(V, Vt);

  // Sb = bf16((Qb @ Kb^T) * inv_scale), batched over 32
  gemm256<0><<<dim3(4, 4, 32), 512, 0, stream>>>(
      Qb, Kb,
      (size_t)LQ * D, (size_t)LK * D, (size_t)LQ * LK,
      inv_scale, Sb, nullptr, nullptr, nullptr);

  softmax_mask<<<32768, 256, 0, stream>>>(Sb, P, Vm);

  // Xb = bf16(Qb + P @ V)
  gemm256<1><<<dim3(4, 4, 32), 512, 0, stream>>>(
      P, Vt,
      (size_t)LQ * LK, (size_t)D * LK, (size_t)LQ * D,
      1.f, Xb, nullptr, Qb, nullptr);

  // hb = bf16(relu(Xb @ W1^T + b1)); M = 32768 folded into blockIdx.y
  gemm256<2><<<dim3(4, 128, 1), 512, 0, stream>>>(
      Xb, W1b, 0, 0, 0,
      1.f, hb, nullptr, nullptr, b1);

  // out = hb @ W2^T + b2 + Xb
  gemm256<3><<<dim3(4, 128, 1), 512, 0, stream>>>(
      hb, W2b, 0, 0, 0,
      1.f, nullptr, out, Xb, b2);
}

// Round 6
// 546.974 us; speedup vs baseline: 1.0452x; 1.0452x over previous
//
#include <hip/hip_runtime.h>
#include <hip/hip_bf16.h>
#include <stdint.h>
#include <math.h>

// ---------------- types / helpers ----------------
typedef __attribute__((ext_vector_type(8))) short bf16x8;   // 8 bf16 in 4 VGPRs
typedef __attribute__((ext_vector_type(4))) float f32x4;

#define AS1 __attribute__((address_space(1)))
#define AS3 __attribute__((address_space(3)))

__device__ __forceinline__ ushort f2bf(float f) {
  union { float f; uint32_t u; } in; in.f = f;
  uint32_t u = in.u;
  uint32_t r = u + 0x7fffu + ((u >> 16) & 1u);   // RNE; inputs finite
  return (ushort)(r >> 16);
}
__device__ __forceinline__ float bf2f(ushort h) {
  union { uint32_t u; float f; } out; out.u = ((uint32_t)h) << 16;
  return out.f;
}

// ---------------- cast f32 -> bf16 (vectorized) ----------------
__global__ __launch_bounds__(256)
void cast_f32_bf16(const float4* __restrict__ in, ushort4* __restrict__ out, int n4) {
  int i = blockIdx.x * blockDim.x + threadIdx.x;
  int stride = gridDim.x * blockDim.x;
  for (; i < n4; i += stride) {
    float4 v = in[i];
    ushort4 o;
    o.x = f2bf(v.x); o.y = f2bf(v.y); o.z = f2bf(v.z); o.w = f2bf(v.w);
    out[i] = o;
  }
}

// ---------------- V (B,LK,D) f32 -> Vt (B,D,LK) bf16 ----------------
__global__ __launch_bounds__(256)
void transpose_cast_v(const float* __restrict__ V, ushort* __restrict__ Vt) {
  __shared__ ushort tile[32][33];                // +1 pad: no bank conflicts
  const int b  = blockIdx.z;
  const int k0 = blockIdx.x * 32;
  const int d0 = blockIdx.y * 32;
  const int tx = threadIdx.x;                    // 0..31
  const int ty = threadIdx.y;                    // 0..7
  const float* Vb = V + ((size_t)b * 1024 + k0) * 1024 + d0;
  #pragma unroll
  for (int r = 0; r < 4; ++r) {
    int k = ty * 4 + r;
    tile[k][tx] = f2bf(Vb[(size_t)k * 1024 + tx]);
  }
  __syncthreads();
  ushort* Vtb = Vt + ((size_t)b * 1024 + d0) * 1024 + k0;
  #pragma unroll
  for (int r = 0; r < 4; ++r) {
    int d = ty * 4 + r;
    Vtb[(size_t)d * 1024 + tx] = tile[tx][d];
  }
}

// ---------------- masked softmax over each (b,q) row of S (bf16 in/out) ----
__global__ __launch_bounds__(256)
void softmax_mask(const ushort* __restrict__ S, ushort* __restrict__ P,
                  const float* __restrict__ mask) {
  const int rowId = blockIdx.x;                  // 0..B*LQ-1
  const int b = rowId >> 10;                     // LQ = 1024
  const ushort4* srow = (const ushort4*)(S + (size_t)rowId * 1024);
  const float4* mrow = (const float4*)(mask + (size_t)b * 1024);
  const int t = threadIdx.x;
  const int wid = t >> 6, lane = t & 63;

  ushort4 sv = srow[t];
  float4 mv = mrow[t];
  float s[4] = {bf2f(sv.x), bf2f(sv.y), bf2f(sv.z), bf2f(sv.w)};
  float m[4] = {mv.x, mv.y, mv.z, mv.w};

  float mx = -INFINITY;
  #pragma unroll
  for (int i = 0; i < 4; ++i) if (m[i] != 0.f) mx = fmaxf(mx, s[i]);
  #pragma unroll
  for (int off = 32; off > 0; off >>= 1)
    mx = fmaxf(mx, __shfl_xor(mx, off));

  __shared__ float wred[4][2];
  if (lane == 0) wred[wid][0] = mx;
  __syncthreads();
  float M = fmaxf(fmaxf(wred[0][0], wred[1][0]), fmaxf(wred[2][0], wred[3][0]));

  float e[4]; float sum = 0.f;
  #pragma unroll
  for (int i = 0; i < 4; ++i) {
    e[i] = (m[i] != 0.f) ? __expf(s[i] - M) : 0.f;
    sum += e[i];
  }
  #pragma unroll
  for (int off = 32; off > 0; off >>= 1)
    sum += __shfl_xor(sum, off);
  if (lane == 0) wred[wid][1] = sum;
  __syncthreads();
  float Z = wred[0][1] + wred[1][1] + wred[2][1] + wred[3][1];
  float inv = (Z > 0.f) ? 1.f / Z : 0.f;

  ushort4 o;
  o.x = f2bf(e[0] * inv); o.y = f2bf(e[1] * inv);
  o.z = f2bf(e[2] * inv); o.w = f2bf(e[3] * inv);
  ((ushort4*)(P + (size_t)rowId * 1024))[t] = o;
}

// ---------------- GEMM 256x256, BK=64, 8 waves, 2-phase double-buffer ------
// C = A(Mx1024,row) * Bt(1024x1024,row)^T.  T3 minimum-2-phase recipe
// (m248-verified at K=1024): per K-tile of 64:
//   STAGE(buf^1, kt+1)  [8 x global_load_lds w=16, issued FIRST]
//   for ks in {0,1}: 12 ds_read_b128 -> lgkmcnt(0)+sched_barrier -> 32 MFMA
//   vmcnt(0) -> barrier -> cur^=1      (one barrier per K-tile)
// LDS 128 KiB: [2 bufs][A,B][256 rows x 64 bf16].  Rows are 128 B.
// T2 swizzle (G4, 128B rows): byte involution y ^= (y>>3)&0x70
// (slot ^= row&7; ds_read lands 2 lanes/bank = free).  Rule #21: linear
// gload_lds dest + inverse-swizzled global source + swizzled ds_read.
// EPI: 0 -> outBf = bf16(acc*scale)                              (S)
//      1 -> outBf = bf16(bf2f(auxBf) + acc)                      (X = Q + PV)
//      2 -> outBf = bf16(relu(acc + bias[col]))                  (FFN1 -> h)
//      3 -> outF  = acc + bias[col] + bf2f(auxBf)                (FFN2 + residual)
template<int EPI>
__global__ __launch_bounds__(512, 2)
void gemm256(const ushort* __restrict__ A, const ushort* __restrict__ Bt,
             size_t aBatch, size_t bBatch, size_t oBatch,
             float scale,
             ushort* outBf, float* outF, const ushort* auxBf,
             const float* __restrict__ bias)
{
  constexpr int K = 1024, N = 1024, NT = 16;    // K-tiles of 64
  __shared__ ushort lds[2][2][16384];           // [buf][A=0,B=1][256*64] = 128 KiB
  const int t = threadIdx.x;
  const int w = t >> 6, lane = t & 63;
  const int wr = w >> 2, wc = w & 3;            // 2 x 4 waves -> 128x64 per wave
  const int lr16 = lane & 15, kg = lane >> 4;

  // T1: XCD-aware bijective remap (nwg is a multiple of 8 for all our grids)
  const unsigned nx = gridDim.x, ny = gridDim.y;
  unsigned flat = blockIdx.x + nx * (blockIdx.y + ny * blockIdx.z);
  const unsigned nwg = nx * ny * gridDim.z;
  const unsigned cpx = nwg >> 3;
  unsigned nf = (flat & 7u) * cpx + (flat >> 3);
  const unsigned bxi = nf % nx;
  const unsigned rest = nf / nx;
  const unsigned byi = rest % ny;
  const unsigned bz = rest / ny;
  const int m0 = byi * 256, n0 = bxi * 256;

  const char* Ab = (const char*)(A + (size_t)bz * aBatch + (size_t)m0 * K);
  const char* Bb = (const char*)(Bt + (size_t)bz * bBatch + (size_t)n0 * K);

  // staging decode: 4 chunks of 16B/lane per matrix per thread.
  // lds-linear byte y = (w*4+i)*1024 + lane*16; unswizzled tile byte
  // tb = y ^ ((y>>3)&0x70); global = (tb>>7)*2048 + (tb&127) + kt*128.
  int gOff[4], lOff[4];
  #pragma unroll
  for (int i = 0; i < 4; ++i) {
    int y = (w * 4 + i) * 1024 + lane * 16;
    int tb = y ^ ((y >> 3) & 0x70);
    gOff[i] = (tb >> 7) * 2048 + (tb & 127);
    lOff[i] = (w * 4 + i) * 1024;               // wave-uniform LDS base (+lane*16 by HW)
  }
  auto STAGE = [&](int buf, int matc, const char* Gb, int kt) {
    #pragma unroll
    for (int i = 0; i < 4; ++i)
      __builtin_amdgcn_global_load_lds(
        (const AS1 void*)(Gb + gOff[i] + kt * 128),
        (AS3 void*)((char*)&lds[buf][matc][0] + lOff[i]), 16, 0, 0);
  };

  // fragment reads (swizzled): row = base + mi*16 + lr16 (row&7 = lr16&7),
  // slot(ks) = (ks*4+kg) ^ (lr16&7); byte = row*128 + slot*16.
  const int sl0 = (kg ^ (lr16 & 7)) << 4;
  const int aBase = (wr * 128 + lr16) * 128 + sl0;
  const int bBase = (wc * 64 + lr16) * 128 + sl0;
  auto LDA = [&](int buf, int mi, int ks) -> bf16x8 {
    return *(const bf16x8*)((const char*)&lds[buf][0][0] + ((aBase + mi * 2048) ^ (ks * 64)));
  };
  auto LDB = [&](int buf, int ni, int ks) -> bf16x8 {
    return *(const bf16x8*)((const char*)&lds[buf][1][0] + ((bBase + ni * 2048) ^ (ks * 64)));
  };

  f32x4 acc[8][4];
  #pragma unroll
  for (int i = 0; i < 8; ++i)
    #pragma unroll
    for (int j = 0; j < 4; ++j)
      acc[i][j] = (f32x4){0.f, 0.f, 0.f, 0.f};

  // prologue: stage tile 0 into buf0, drain, barrier
  STAGE(0, 0, Ab, 0);
  STAGE(0, 1, Bb, 0);
  asm volatile("s_waitcnt vmcnt(0)" ::: "memory");
  __builtin_amdgcn_s_barrier();

  int cur = 0;
  #pragma unroll 1
  for (int kt = 0; kt < NT; ++kt) {
    // issue next-tile staging FIRST (hides under this tile's 64 MFMAs)
    int nk = kt + 1 < NT ? kt + 1 : NT - 1;     // last iter: benign dummy re-stage
    STAGE(cur ^ 1, 0, Ab, nk);
    STAGE(cur ^ 1, 1, Bb, nk);
    #pragma unroll
    for (int ks = 0; ks < 2; ++ks) {
      bf16x8 af0 = LDA(cur, 0, ks), af1 = LDA(cur, 1, ks);
      bf16x8 af2 = LDA(cur, 2, ks), af3 = LDA(cur, 3, ks);
      bf16x8 af4 = LDA(cur, 4, ks), af5 = LDA(cur, 5, ks);
      bf16x8 af6 = LDA(cur, 6, ks), af7 = LDA(cur, 7, ks);
      bf16x8 bf0 = LDB(cur, 0, ks), bf1 = LDB(cur, 1, ks);
      bf16x8 bf2 = LDB(cur, 2, ks), bf3 = LDB(cur, 3, ks);
      asm volatile("s_waitcnt lgkmcnt(0)" ::: "memory");
      __builtin_amdgcn_sched_barrier(0);
      __builtin_amdgcn_s_setprio(1);
      acc[0][0] = __builtin_amdgcn_mfma_f32_16x16x32_bf16(af0, bf0, acc[0][0], 0, 0, 0);
      acc[0][1] = __builtin_amdgcn_mfma_f32_16x16x32_bf16(af0, bf1, acc[0][1], 0, 0, 0);
      acc[0][2] = __builtin_amdgcn_mfma_f32_16x16x32_bf16(af0, bf2, acc[0][2], 0, 0, 0);
      acc[0][3] = __builtin_amdgcn_mfma_f32_16x16x32_bf16(af0, bf3, acc[0][3], 0, 0, 0);
      acc[1][0] = __builtin_amdgcn_mfma_f32_16x16x32_bf16(af1, bf0, acc[1][0], 0, 0, 0);
      acc[1][1] = __builtin_amdgcn_mfma_f32_16x16x32_bf16(af1, bf1, acc[1][1], 0, 0, 0);
      acc[1][2] = __builtin_amdgcn_mfma_f32_16x16x32_bf16(af1, bf2, acc[1][2], 0, 0, 0);
      acc[1][3] = __builtin_amdgcn_mfma_f32_16x16x32_bf16(af1, bf3, acc[1][3], 0, 0, 0);
      acc[2][0] = __builtin_amdgcn_mfma_f32_16x16x32_bf16(af2, bf0, acc[2][0], 0, 0, 0);
      acc[2][1] = __builtin_amdgcn_mfma_f32_16x16x32_bf16(af2, bf1, acc[2][1], 0, 0, 0);
      acc[2][2] = __builtin_amdgcn_mfma_f32_16x16x32_bf16(af2, bf2, acc[2][2], 0, 0, 0);
      acc[2][3] = __builtin_amdgcn_mfma_f32_16x16x32_bf16(af2, bf3, acc[2][3], 0, 0, 0);
      acc[3][0] = __builtin_amdgcn_mfma_f32_16x16x32_bf16(af3, bf0, acc[3][0], 0, 0, 0);
      acc[3][1] = __builtin_amdgcn_mfma_f32_16x16x32_bf16(af3, bf1, acc[3][1], 0, 0, 0);
      acc[3][2] = __builtin_amdgcn_mfma_f32_16x16x32_bf16(af3, bf2, acc[3][2], 0, 0, 0);
      acc[3][3] = __builtin_amdgcn_mfma_f32_16x16x32_bf16(af3, bf3, acc[3][3], 0, 0, 0);
      acc[4][0] = __builtin_amdgcn_mfma_f32_16x16x32_bf16(af4, bf0, acc[4][0], 0, 0, 0);
      acc[4][1] = __builtin_amdgcn_mfma_f32_16x16x32_bf16(af4, bf1, acc[4][1], 0, 0, 0);
      acc[4][2] = __builtin_amdgcn_mfma_f32_16x16x32_bf16(af4, bf2, acc[4][2], 0, 0, 0);
      acc[4][3] = __builtin_amdgcn_mfma_f32_16x16x32_bf16(af4, bf3, acc[4][3], 0, 0, 0);
      acc[5][0] = __builtin_amdgcn_mfma_f32_16x16x32_bf16(af5, bf0, acc[5][0], 0, 0, 0);
      acc[5][1] = __builtin_amdgcn_mfma_f32_16x16x32_bf16(af5, bf1, acc[5][1], 0, 0, 0);
      acc[5][2] = __builtin_amdgcn_mfma_f32_16x16x32_bf16(af5, bf2, acc[5][2], 0, 0, 0);
      acc[5][3] = __builtin_amdgcn_mfma_f32_16x16x32_bf16(af5, bf3, acc[5][3], 0, 0, 0);
      acc[6][0] = __builtin_amdgcn_mfma_f32_16x16x32_bf16(af6, bf0, acc[6][0], 0, 0, 0);
      acc[6][1] = __builtin_amdgcn_mfma_f32_16x16x32_bf16(af6, bf1, acc[6][1], 0, 0, 0);
      acc[6][2] = __builtin_amdgcn_mfma_f32_16x16x32_bf16(af6, bf2, acc[6][2], 0, 0, 0);
      acc[6][3] = __builtin_amdgcn_mfma_f32_16x16x32_bf16(af6, bf3, acc[6][3], 0, 0, 0);
      acc[7][0] = __builtin_amdgcn_mfma_f32_16x16x32_bf16(af7, bf0, acc[7][0], 0, 0, 0);
      acc[7][1] = __builtin_amdgcn_mfma_f32_16x16x32_bf16(af7, bf1, acc[7][1], 0, 0, 0);
      acc[7][2] = __builtin_amdgcn_mfma_f32_16x16x32_bf16(af7, bf2, acc[7][2], 0, 0, 0);
      acc[7][3] = __builtin_amdgcn_mfma_f32_16x16x32_bf16(af7, bf3, acc[7][3], 0, 0, 0);
      __builtin_amdgcn_s_setprio(0);
    }
    // stage for tile kt+1 must have fully landed before next iter's ds_reads
    asm volatile("s_waitcnt vmcnt(0)" ::: "memory");
    __builtin_amdgcn_s_barrier();
    cur ^= 1;
  }

  // epilogue: C/D layout col=lane&15, row=(lane>>4)*4+j  [m89-verified]
  const int lr4 = kg * 4;
  #pragma unroll
  for (int mi = 0; mi < 8; ++mi) {
    #pragma unroll
    for (int ni = 0; ni < 4; ++ni) {
      int row = m0 + wr * 128 + mi * 16 + lr4;
      int col = n0 + wc * 64 + ni * 16 + lr16;
      size_t o = (size_t)bz * oBatch + (size_t)row * N + col;
      f32x4 v = acc[mi][ni];
      #pragma unroll
      for (int j = 0; j < 4; ++j) {
        size_t oo = o + (size_t)j * N;
        float x = v[j];
        if (EPI == 0) {
          outBf[oo] = f2bf(x * scale);
        } else if (EPI == 1) {
          outBf[oo] = f2bf(bf2f(auxBf[oo]) + x);
        } else if (EPI == 2) {
          float h = x + bias[col];
          h = h > 0.f ? h : 0.f;
          outBf[oo] = f2bf(h);
        } else {
          outF[oo] = x + bias[col] + bf2f(auxBf[oo]);
        }
      }
    }
  }
}

// ---------------- launch ----------------
extern "C" void kernel_launch(void* const* d_in, const int* in_sizes, int n_in,
                              void* d_out, int out_size, void* d_ws, size_t ws_size,
                              hipStream_t stream) {
  (void)in_sizes; (void)n_in; (void)out_size; (void)ws_size;
  const float* Q  = (const float*)d_in[0];
  const float* Km = (const float*)d_in[1];
  const float* V  = (const float*)d_in[2];
  const float* Vm = (const float*)d_in[3];
  const float* W1 = (const float*)d_in[4];
  const float* b1 = (const float*)d_in[5];
  const float* W2 = (const float*)d_in[6];
  const float* b2 = (const float*)d_in[7];
  float* out = (float*)d_out;

  const int LQ = 1024, LK = 1024, D = 1024;
  const size_t NQ = (size_t)32 * LQ * D;            // 33.5M elems

  // workspace layout (MiB offsets): Qb 0..64, Kb/hb 64..128, Vt 128..192,
  // Sb 192..256, P 256..320, Xb 320..384, W1b 384..386, W2b 386..388
  char* ws = (char*)d_ws;
  ushort* Qb  = (ushort*)(ws);
  ushort* Kb  = (ushort*)(ws + ((size_t)64 << 20));
  ushort* hb  = Kb;                                  // reuse (Kb dead after S-GEMM)
  ushort* Vt  = (ushort*)(ws + ((size_t)128 << 20));
  ushort* Sb  = (ushort*)(ws + ((size_t)192 << 20));
  ushort* P   = (ushort*)(ws + ((size_t)256 << 20));
  ushort* Xb  = (ushort*)(ws + ((size_t)320 << 20));
  ushort* W1b = (ushort*)(ws + ((size_t)384 << 20));
  ushort* W2b = (ushort*)(ws + ((size_t)386 << 20));

  const float inv_scale = 1.0f / (sqrtf(1024.0f) + 1e-8f);

  cast_f32_bf16<<<2048, 256, 0, stream>>>((const float4*)Q,  (ushort4*)Qb, (int)(NQ / 4));
  cast_f32_bf16<<<2048, 256, 0, stream>>>((const float4*)Km, (ushort4*)Kb, (int)(NQ / 4));
  cast_f32_bf16<<<256, 256, 0, stream>>>((const float4*)W1, (ushort4*)W1b, (1024 * 1024) / 4);
  cast_f32_bf16<<<256, 256, 0, stream>>>((const float4*)W2, (ushort4*)W2b, (1024 * 1024) / 4);
  transpose_cast_v<<<dim3(32, 32, 32), dim3(32, 8), 0, stream>>>(V, Vt);

  // Sb = bf16((Qb @ Kb^T) * inv_scale), batched over 32
  gemm256<0><<<dim3(4, 4, 32), 512, 0, stream>>>(
      Qb, Kb,
      (size_t)LQ * D, (size_t)LK * D, (size_t)LQ * LK,
      inv_scale, Sb, nullptr, nullptr, nullptr);

  softmax_mask<<<32768, 256, 0, stream>>>(Sb, P, Vm);

  // Xb = bf16(Qb + P @ V)
  gemm256<1><<<dim3(4, 4, 32), 512, 0, stream>>>(
      P, Vt,
      (size_t)LQ * LK, (size_t)D * LK, (size_t)LQ * D,
      1.f, Xb, nullptr, Qb, nullptr);

  // hb = bf16(relu(Xb @ W1^T + b1)); M = 32768 folded into blockIdx.y
  gemm256<2><<<dim3(4, 128, 1), 512, 0, stream>>>(
      Xb, W1b, 0, 0, 0,
      1.f, hb, nullptr, nullptr, b1);

  // out = hb @ W2^T + b2 + Xb
  gemm256<3><<<dim3(4, 128, 1), 512, 0, stream>>>(
      hb, W2b, 0, 0, 0,
      1.f, nullptr, out, Xb, b2);
}